// Round 5
// baseline (9578.880 us; speedup 1.0000x reference)
//
#include <hip/hip_runtime.h>

// 2-layer LSTM (B=256,T=512,D=64,H=512) + FC(last step), MI355X gfx950.
// Round 5: split-role persistent grid, low register footprint (no spills).
//   512 blocks x 256 thr, 2 blocks/CU (launch_bounds(256,2) -> 256-reg cap
//   under either arg2 semantics; rounds 3/4 proved 512-thr blocks pin to 128
//   regs and spill 3.2 GB/launch).
//   Blocks 0..255   = L0: (g of 8)x(s of 32): 32 rows x 16 h-dims. Each wave
//     owns a K-quarter of K=512(h)+64(x), weights 20 frags = 80 VGPR.
//   Blocks 256..511 = L1: (G of 4)x(s1 of 64): 64 rows x 8 h-dims. Each wave
//     owns a K-quarter of K=1024 (h0|h1), weights 16 frags = 64 VGPR.
//   L1 trails L0 by one step. Cross-block h via relaxed agent atomics (IF$),
//   per-block epoch FLAG ARRAYS (plain stores; wave64 polls), lag-1
//   backpressure flags for ping-pong overwrite safety.

#define BATCH 256
#define SEQ   512
#define DIN   64
#define HID   512

typedef _Float16 f16_t;
typedef __attribute__((ext_vector_type(8))) _Float16 f16x8;
typedef __attribute__((ext_vector_type(4))) float    f32x4;

#define SCOPE_AGT __HIP_MEMORY_SCOPE_AGENT

__device__ inline f16x8 cvt8(const float* __restrict__ p) {
    f16x8 r;
#pragma unroll
    for (int j = 0; j < 8; j++) r[j] = (_Float16)p[j];
    return r;
}

__device__ inline f16x8 cvt8v(f32x4 lo, f32x4 hi) {
    f16x8 r;
#pragma unroll
    for (int j = 0; j < 4; j++) { r[j] = (_Float16)lo[j]; r[4 + j] = (_Float16)hi[j]; }
    return r;
}

// 16B load at the coherence point (2x u64 relaxed agent atomics).
__device__ inline f16x8 ldx8(const f16_t* p) {
    const unsigned long long* q = (const unsigned long long*)p;
    unsigned long long a = __hip_atomic_load(q,     __ATOMIC_RELAXED, SCOPE_AGT);
    unsigned long long b = __hip_atomic_load(q + 1, __ATOMIC_RELAXED, SCOPE_AGT);
    union { unsigned long long u[2]; f16x8 v; } c;
    c.u[0] = a; c.u[1] = b;
    return c.v;
}

__device__ inline void sth2(f16_t* base_even, float h, float hn) {
    union { struct { _Float16 lo, hi; } s; unsigned u; } pk;
    pk.s.lo = (_Float16)h; pk.s.hi = (_Float16)hn;
    __hip_atomic_store((unsigned*)base_even, pk.u, __ATOMIC_RELAXED, SCOPE_AGT);
}

// Whole wave polls flag array element `p[i]` (i = this lane's index).
__device__ inline void pollw(unsigned* p, unsigned need) {
    for (;;) {
        unsigned v = __hip_atomic_load(p, __ATOMIC_RELAXED, SCOPE_AGT);
        if (__all((int)(v >= need))) break;
        __builtin_amdgcn_s_sleep(1);
    }
}

__device__ inline float sgm(float v) { return 1.f / (1.f + __expf(-v)); }
__device__ inline float th(float v)  { return 1.f - 2.f / (__expf(2.f * v) + 1.f); }

__global__ __launch_bounds__(256, 2) void lstm_pipe(
    const float* __restrict__ x,
    const float* __restrict__ wih0, const float* __restrict__ whh0,
    const float* __restrict__ bih0, const float* __restrict__ bhh0,
    const float* __restrict__ wih1, const float* __restrict__ whh1,
    const float* __restrict__ bih1, const float* __restrict__ bhh1,
    unsigned* __restrict__ f0, unsigned* __restrict__ f1,
    f16_t* __restrict__ h1buf, f16_t* __restrict__ h0buf)
{
    __shared__ f32x4 red[4][8][64];      // [wave][acc-slot][lane]  32 KB

    const int tid  = threadIdx.x;
    const int w    = tid >> 6, lane = tid & 63;
    const int quad = lane >> 4, col = lane & 15;
    const int bid  = blockIdx.x;

    if (bid < 256) {
        // ======================= L0 block: (g, s) =======================
        const int g = bid & 7, s = bid >> 3;
        unsigned* myf0 = f0 + g * 32;
        unsigned* bp1  = f1 + (g >> 1) * 64;     // backpressure: L1 group g/2

        f16x8 Wb[20];
#pragma unroll
        for (int i = 0; i < 4; i++) {            // h K-blocks: kb = w*4+i
            const int k0 = (w * 4 + i) * 32 + quad * 8;
#pragma unroll
            for (int nt = 0; nt < 4; nt++) {
                const int gr = nt * HID + s * 16 + col;
                Wb[i * 4 + nt] = cvt8(whh0 + (size_t)gr * HID + k0);
            }
        }
        if (w < 2) {                             // x K-block: d = w*32..+32
#pragma unroll
            for (int nt = 0; nt < 4; nt++) {
                const int gr = nt * HID + s * 16 + col;
                Wb[16 + nt] = cvt8(wih0 + (size_t)gr * DIN + w * 32 + quad * 8);
            }
        } else {
#pragma unroll
            for (int nt = 0; nt < 4; nt++) Wb[16 + nt] = (f16x8)(_Float16)0;
        }
#pragma unroll
        for (int i = 0; i < 20; i++) asm volatile("" : "+v"(Wb[i]));  // anti-remat

        float bias[4] = {0, 0, 0, 0};
        if (w < 2) {
#pragma unroll
            for (int nt = 0; nt < 4; nt++) {
                const int gr = nt * HID + s * 16 + col;
                bias[nt] = bih0[gr] + bhh0[gr];
            }
        }
        float cst[4] = {0, 0, 0, 0};

        for (int it = 0; it < SEQ; ++it) {
            // x prefetch (before polls; independent)
            f32x4 xr[4];
            if (w < 2) {
#pragma unroll
                for (int m = 0; m < 2; m++) {
                    const float* px = x + ((size_t)(g * 32 + m * 16 + col) * SEQ + it) * DIN + w * 32 + quad * 8;
                    xr[m * 2]     = *(const f32x4*)px;
                    xr[m * 2 + 1] = *(const f32x4*)(px + 4);
                }
            }
            if (it >= 1) {
                pollw(myf0 + (lane & 31), (unsigned)it);          // h0[it-1] ready
                if (it >= 2) pollw(bp1 + lane, (unsigned)(it - 1)); // L1 past reads of slot it&1
            }

            f32x4 acc[8];
#pragma unroll
            for (int j = 0; j < 8; j++) acc[j] = (f32x4){0.f, 0.f, 0.f, 0.f};

            if (it > 0) {
                const f16_t* h0b = h0buf + (size_t)((it - 1) & 1) * BATCH * HID;
#pragma unroll
                for (int i = 0; i < 4; i++) {
                    const int kb = w * 4 + i;
#pragma unroll
                    for (int m = 0; m < 2; m++) {
                        f16x8 a = ldx8(h0b + (size_t)(g * 32 + m * 16 + col) * HID + kb * 32 + quad * 8);
#pragma unroll
                        for (int nt = 0; nt < 4; nt++)
                            acc[m * 4 + nt] = __builtin_amdgcn_mfma_f32_16x16x32_f16(a, Wb[i * 4 + nt], acc[m * 4 + nt], 0, 0, 0);
                    }
                }
            }
            if (w < 2) {
#pragma unroll
                for (int m = 0; m < 2; m++) {
                    f16x8 a = cvt8v(xr[m * 2], xr[m * 2 + 1]);
#pragma unroll
                    for (int nt = 0; nt < 4; nt++)
                        acc[m * 4 + nt] = __builtin_amdgcn_mfma_f32_16x16x32_f16(a, Wb[16 + nt], acc[m * 4 + nt], 0, 0, 0);
                }
            }
#pragma unroll
            for (int j = 0; j < 8; j++) red[w][j][lane] = acc[j];
            __syncthreads();                                      // partials published

            if (w < 2) {                                          // cell: wave w -> m-tile w
                const int m = w;
                f32x4 gate[4];
#pragma unroll
                for (int nt = 0; nt < 4; nt++) {
                    f32x4 v = red[0][m * 4 + nt][lane];
#pragma unroll
                    for (int ww = 1; ww < 4; ww++) {
                        f32x4 p = red[ww][m * 4 + nt][lane];
#pragma unroll
                        for (int r = 0; r < 4; r++) v[r] += p[r];
                    }
                    gate[nt] = v;
                }
                f16_t* hout = h0buf + (size_t)(it & 1) * BATCH * HID;
#pragma unroll
                for (int r = 0; r < 4; r++) {
                    float iv = sgm(gate[0][r] + bias[0]), fv = sgm(gate[1][r] + bias[1]);
                    float gv = th(gate[2][r] + bias[2]),  ov = sgm(gate[3][r] + bias[3]);
                    float c = fv * cst[r] + iv * gv;
                    cst[r] = c;
                    float h = ov * th(c);
                    float hn = __shfl_down(h, 1);
                    if ((lane & 1) == 0)
                        sth2(hout + (size_t)(g * 32 + m * 16 + quad * 4 + r) * HID + s * 16 + col, h, hn);
                }
            }
            __syncthreads();                                      // drain h stores (vmcnt 0)
            if (tid == 0)
                __hip_atomic_store(myf0 + s, (unsigned)(it + 1), __ATOMIC_RELAXED, SCOPE_AGT);
        }
    } else {
        // ======================= L1 block: (G, s1) ======================
        const int idx = bid - 256;
        const int G = idx & 3, s1 = idx >> 2;
        unsigned* myf1 = f1 + G * 64;

        f16x8 Wb[16];
#pragma unroll
        for (int i = 0; i < 8; i++) {            // kb = w*8+i over K=1024
            const int kb = w * 8 + i;
            const int k0 = kb * 32 + quad * 8;
#pragma unroll
            for (int n2 = 0; n2 < 2; n2++) {
                const int gate = n2 * 2 + (col >> 3);
                const int grow = gate * HID + s1 * 8 + (col & 7);
                const float* src = (kb < 16) ? (wih1 + (size_t)grow * HID + k0)
                                             : (whh1 + (size_t)grow * HID + (k0 - 512));
                Wb[i * 2 + n2] = cvt8(src);
            }
        }
#pragma unroll
        for (int i = 0; i < 16; i++) asm volatile("" : "+v"(Wb[i]));  // anti-remat

        const int d = s1 * 8 + (col & 7);
        const float bi = bih1[d] + bhh1[d];
        const float bf = bih1[HID + d] + bhh1[HID + d];
        const float bg = bih1[2 * HID + d] + bhh1[2 * HID + d];
        const float bo = bih1[3 * HID + d] + bhh1[3 * HID + d];
        float cst[4] = {0, 0, 0, 0};

        for (int it = 1; it <= SEQ; ++it) {
            const int t = it - 1;
            pollw(f0 + (2 * G + (lane >> 5)) * 32 + (lane & 31), (unsigned)it);  // h0[t] ready
            if (it >= 2) pollw(myf1 + lane, (unsigned)(it - 1));                 // h1[t-1] ready + overwrite-safe

            f32x4 acc[8];
#pragma unroll
            for (int j = 0; j < 8; j++) acc[j] = (f32x4){0.f, 0.f, 0.f, 0.f};

            const f16_t* h0b = h0buf + (size_t)(t & 1) * BATCH * HID;
            const f16_t* h1r = h1buf + (size_t)((t - 1) & 1) * BATCH * HID;
#pragma unroll
            for (int i = 0; i < 8; i++) {
                const int kb = w * 8 + i;
                if (kb < 16) {
#pragma unroll
                    for (int mt = 0; mt < 4; mt++) {
                        f16x8 a = ldx8(h0b + (size_t)(G * 64 + mt * 16 + col) * HID + kb * 32 + quad * 8);
#pragma unroll
                        for (int n2 = 0; n2 < 2; n2++)
                            acc[mt * 2 + n2] = __builtin_amdgcn_mfma_f32_16x16x32_f16(a, Wb[i * 2 + n2], acc[mt * 2 + n2], 0, 0, 0);
                    }
                } else if (t > 0) {
#pragma unroll
                    for (int mt = 0; mt < 4; mt++) {
                        f16x8 a = ldx8(h1r + (size_t)(G * 64 + mt * 16 + col) * HID + (kb - 16) * 32 + quad * 8);
#pragma unroll
                        for (int n2 = 0; n2 < 2; n2++)
                            acc[mt * 2 + n2] = __builtin_amdgcn_mfma_f32_16x16x32_f16(a, Wb[i * 2 + n2], acc[mt * 2 + n2], 0, 0, 0);
                    }
                }
            }
#pragma unroll
            for (int j = 0; j < 8; j++) red[w][j][lane] = acc[j];
            __syncthreads();                                      // partials published

            {                                                     // cell: wave w -> m-tile w
                const int mt = w;
                f32x4 t0 = red[0][mt * 2][lane], t1 = red[0][mt * 2 + 1][lane];
#pragma unroll
                for (int ww = 1; ww < 4; ww++) {
                    f32x4 p0 = red[ww][mt * 2][lane], p1 = red[ww][mt * 2 + 1][lane];
#pragma unroll
                    for (int r = 0; r < 4; r++) { t0[r] += p0[r]; t1[r] += p1[r]; }
                }
                f16_t* hout = h1buf + (size_t)(t & 1) * BATCH * HID;
#pragma unroll
                for (int r = 0; r < 4; r++) {
                    // lanes col<8 hold gates i (t0) and g (t1); partners col+8 hold f,o
                    float p0 = __shfl_xor(t0[r], 8), p1 = __shfl_xor(t1[r], 8);
                    float iv = sgm(t0[r] + bi), fv = sgm(p0 + bf);
                    float gv = th(t1[r] + bg),  ov = sgm(p1 + bo);
                    float c = fv * cst[r] + iv * gv;                // garbage in col>=8 lanes (unused)
                    cst[r] = c;
                    float h = ov * th(c);
                    float hn = __shfl_down(h, 1);
                    if ((col & 9) == 0)                             // col even and < 8
                        sth2(hout + (size_t)(G * 64 + mt * 16 + quad * 4 + r) * HID + s1 * 8 + col, h, hn);
                }
            }
            __syncthreads();                                      // drain h stores
            if (tid == 0)
                __hip_atomic_store(myf1 + s1, (unsigned)it, __ATOMIC_RELAXED, SCOPE_AGT);
        }
    }
}

// out[b] = dot(h1[511][b], fc_w) + fc_b ; slot = 511&1 = 1.
__global__ void fc_k(const f16_t* __restrict__ h1buf, const float* __restrict__ fcw,
                     const float* __restrict__ fcb, float* __restrict__ out)
{
    const int b = blockIdx.x, lane = threadIdx.x;
    const f16_t* hp = h1buf + ((size_t)(BATCH + b)) * HID;
    float sum = 0.f;
#pragma unroll
    for (int j = 0; j < 8; j++) {
        const int k = lane * 8 + j;
        sum += (float)hp[k] * fcw[k];
    }
#pragma unroll
    for (int off = 32; off; off >>= 1) sum += __shfl_down(sum, off);
    if (lane == 0) out[b] = sum + fcb[0];
}

extern "C" void kernel_launch(void* const* d_in, const int* in_sizes, int n_in,
                              void* d_out, int out_size, void* d_ws, size_t ws_size,
                              hipStream_t stream)
{
    const float* x    = (const float*)d_in[0];
    const float* wih0 = (const float*)d_in[1];
    const float* whh0 = (const float*)d_in[2];
    const float* bih0 = (const float*)d_in[3];
    const float* bhh0 = (const float*)d_in[4];
    const float* wih1 = (const float*)d_in[5];
    const float* whh1 = (const float*)d_in[6];
    const float* bih1 = (const float*)d_in[7];
    const float* bhh1 = (const float*)d_in[8];
    const float* fcw  = (const float*)d_in[9];
    const float* fcb  = (const float*)d_in[10];
    float* out = (float*)d_out;

    unsigned char* ws = (unsigned char*)d_ws;
    unsigned* f0 = (unsigned*)ws;                 // 8*32 dwords = 1 KB
    unsigned* f1 = (unsigned*)(ws + 1024);        // 4*64 dwords = 1 KB
    f16_t* h1buf = (f16_t*)(ws + 4096);           // 2 slots * 256*512 f16 = 512 KB
    f16_t* h0buf = (f16_t*)(ws + 4096 + 2 * BATCH * HID * sizeof(f16_t));  // 512 KB

    hipMemsetAsync(ws, 0, 4096, stream);          // zero epoch flags
    lstm_pipe<<<dim3(512), dim3(256), 0, stream>>>(x, wih0, whh0, bih0, bhh0,
                                                   wih1, whh1, bih1, bhh1,
                                                   f0, f1, h1buf, h0buf);
    fc_k<<<dim3(BATCH), dim3(64), 0, stream>>>(h1buf, fcw, fcb, out);
}